// Round 9
// baseline (360.410 us; speedup 1.0000x reference)
//
#include <hip/hip_runtime.h>
#include <math.h>

#define DD    64
#define TT    256
#define NROW  4096
#define BLK   256
#define GRID  256          // 256 row-tiles of 16, 1 block/CU, 4 waves = 1/SIMD

typedef __attribute__((ext_vector_type(8))) short  short8;
typedef __attribute__((ext_vector_type(4))) float  f32x4;

// Raw workgroup barrier: LDS visibility only (lgkmcnt drain), no vmcnt drain.
// Global loads/stores ride across (T4). sched_barrier(0) per rule #18.
#define BARRIER() do {                                        \
    asm volatile("s_waitcnt lgkmcnt(0)" ::: "memory");        \
    __builtin_amdgcn_sched_barrier(0);                        \
    __builtin_amdgcn_s_barrier();                             \
    __builtin_amdgcn_sched_barrier(0);                        \
  } while (0)

__device__ __forceinline__ float fexp2(float x) {
  float r;
  asm("v_exp_f32 %0, %1" : "=v"(r) : "v"(x));
  return r;
}

__device__ __forceinline__ unsigned short f2bf(float f) {
  unsigned u = __builtin_bit_cast(unsigned, f);
  u += 0x7fffu + ((u >> 16) & 1u);          // round-to-nearest-even
  return (unsigned short)(u >> 16);
}

__device__ __forceinline__ unsigned long long pack4(f32x4 v) {
  return (unsigned long long)f2bf(v[0])
       | ((unsigned long long)f2bf(v[1]) << 16)
       | ((unsigned long long)f2bf(v[2]) << 32)
       | ((unsigned long long)f2bf(v[3]) << 48);
}

__device__ __forceinline__ short8 pack_frag(f32x4 a, f32x4 b) {
  short8 r;
  r[0] = (short)f2bf(a[0]); r[1] = (short)f2bf(a[1]);
  r[2] = (short)f2bf(a[2]); r[3] = (short)f2bf(a[3]);
  r[4] = (short)f2bf(b[0]); r[5] = (short)f2bf(b[1]);
  r[6] = (short)f2bf(b[2]); r[7] = (short)f2bf(b[3]);
  return r;
}

__device__ __forceinline__ short8 load_wfrag(const float* p) {
  f32x4 a = *(const f32x4*)p;
  f32x4 b = *(const f32x4*)(p + 4);
  return pack_frag(a, b);
}

// weight fragment with scalar scale folded in (for exp2-form gates)
__device__ __forceinline__ short8 load_wfrag_s(const float* p, float s) {
  f32x4 a = *(const f32x4*)p * s;
  f32x4 b = *(const f32x4*)(p + 4) * s;
  return pack_frag(a, b);
}

// A&S 7.1.26 erf, max abs err 1.5e-7
__device__ __forceinline__ float ferf(float x) {
  float ax = fabsf(x);
  float t  = __builtin_amdgcn_rcpf(fmaf(0.3275911f, ax, 1.0f));
  float p  = fmaf(1.061405429f, t, -1.453152027f);
  p = fmaf(p, t, 1.421413741f);
  p = fmaf(p, t, -0.284496736f);
  p = fmaf(p, t, 0.254829592f);
  p = p * t;
  float y = 1.0f - p * fexp2(ax * ax * -1.44269504f);
  return copysignf(y, x);
}

// bias_t[t][j] = msg_b[j] + sum_d cos(t*freq[d]+phase[d]) * msg_W[j][128+d]
__global__ void bias_kernel(const float* __restrict__ msg_W,
                            const float* __restrict__ msg_b,
                            const float* __restrict__ freq,
                            const float* __restrict__ phase,
                            float* __restrict__ bias_t) {
  __shared__ float teL[DD];
  const int t = blockIdx.x;
  const int j = threadIdx.x;
  teL[j] = cosf(fmaf((float)t, freq[j], phase[j]));
  __syncthreads();
  float acc = msg_b[j];
  const float* wrow = msg_W + j * 192 + 128;
  #pragma unroll 8
  for (int k = 0; k < DD; ++k) acc = fmaf(teL[k], wrow[k], acc);
  bias_t[t * DD + j] = acc;
}

__launch_bounds__(BLK, 1)
__global__ void scan9(const float* __restrict__ x,
                      const int*   __restrict__ mask,
                      const float* __restrict__ msg_W,
                      const float* __restrict__ W_ih,
                      const float* __restrict__ W_hh,
                      const float* __restrict__ b_ih,
                      const float* __restrict__ b_hh,
                      const float* __restrict__ bias_t,
                      float* __restrict__ out) {
  // bf16 tiles: stride 72 shorts (144 B) -> <=2-way banks on b128 frag reads
  __shared__ alignas(16) unsigned short xs[16 * 72];
  __shared__ alignas(16) unsigned short ss[16 * 72];
  __shared__ alignas(16) unsigned short ms[16 * 72];
  __shared__ alignas(16) float s0t[16 * 68];    // one-time s0 handoff (fp32)
  __shared__ int tr_lds[TT];

  const int tid  = threadIdx.x;
  const int lane = tid & 63;
  const int wv   = tid >> 6;       // 4 waves, each owns cols [16wv, 16wv+16)
  const int col  = lane & 15;
  const int kh   = lane >> 4;
  const int n    = wv * 16 + col;
  const int row0 = blockIdx.x * 16;

  tr_lds[tid] = tid * mask[tid];   // BLK == TT

  // ---- weight fragments (every wave holds msg/ih/hh for its col slice) ----
  // exp2-form gates: fold -log2e into r,z rows; +2*log2e into n rows.
  const float SC_RZ = -1.44269504f, SC_N = 2.88539008f;
  short8 wm[4], wi[3][2], wh[3][2];
  {
    const float* mrow = msg_W + (size_t)n * 192;
    #pragma unroll
    for (int kf = 0; kf < 4; ++kf) wm[kf] = load_wfrag(mrow + kf * 32 + kh * 8);
    const float sc[3] = {SC_RZ, SC_RZ, SC_N};
    #pragma unroll
    for (int p = 0; p < 3; ++p) {
      const float* irow = W_ih + (size_t)(p * 64 + n) * 64;
      const float* hrow = W_hh + (size_t)(p * 64 + n) * 64;
      #pragma unroll
      for (int kf = 0; kf < 2; ++kf) {
        wi[p][kf] = load_wfrag_s(irow + kf * 32 + kh * 8, sc[p]);
        wh[p][kf] = load_wfrag_s(hrow + kf * 32 + kh * 8, sc[p]);
      }
    }
  }
  const float bsum0 = (b_ih[n]       + b_hh[n])       * SC_RZ;  // r-gate bias
  const float bsum1 = (b_ih[64 + n]  + b_hh[64 + n])  * SC_RZ;  // z-gate bias
  const float bih2  =  b_ih[128 + n] * SC_N;
  const float bhh2  =  b_hh[128 + n] * SC_N;

  // staging map: 256 threads cover 16 rows x 16 float4
  const int fr = tid >> 4;
  const int fd = (tid & 15) * 4;

  // ---- s0 = mean over t (each thread owns (fr,fd); no reduction needed) ----
  {
    const float* px = x + (size_t)(row0 + fr) * DD + fd;
    f32x4 a0 = {0.f,0.f,0.f,0.f}, a1 = {0.f,0.f,0.f,0.f};
    #pragma unroll 4
    for (int t = 0; t < TT; t += 2) {          // 2 accumulators for ILP
      a0 += *(const f32x4*)(px + (size_t)t * (NROW * DD));
      a1 += *(const f32x4*)(px + (size_t)(t + 1) * (NROW * DD));
    }
    f32x4 m = (a0 + a1) * (1.0f / 256.0f);
    *(f32x4*)&s0t[fr * 68 + fd] = m;
    *(unsigned long long*)&ss[fr * 72 + fd] = pack4(m);
    f32x4 xv0 = *(const f32x4*)px;             // tr[0] = 0
    *(unsigned long long*)&xs[fr * 72 + fd] = pack4(xv0);
  }
  __syncthreads();

  // per-lane fp32 state + first bias
  float s_reg[4];
  #pragma unroll
  for (int i = 0; i < 4; ++i) s_reg[i] = s0t[(kh * 4 + i) * 68 + n];
  float btc = bias_t[n];                       // tr[0] = 0

  // 2-deep x pipeline (issued ph1(t), consumed ph2(t+1))
  f32x4 xvA = {0.f,0.f,0.f,0.f}, xvB = {0.f,0.f,0.f,0.f};
  xvA = *(const f32x4*)(x + ((size_t)tr_lds[1] * NROW + row0 + fr) * DD + fd);

  auto body = [&](int t, f32x4& xv_use, f32x4& xv_load) {
    // ================= PHASE 1 =================
    // fire-and-forget: x(tr[t+2]) load + next bias (ride across barriers)
    if (t + 2 < TT)
      xv_load = *(const f32x4*)(x + ((size_t)tr_lds[t + 2] * NROW + row0 + fr) * DD + fd);
    float btn = 0.f;
    if (t + 1 < TT) btn = bias_t[tr_lds[t + 1] * DD + n];

    // A-fragments
    const unsigned short* ax = &xs[(lane & 15) * 72];
    const unsigned short* as = &ss[(lane & 15) * 72];
    short8 xa0 = *(const short8*)(ax + kh * 8);
    short8 xa1 = *(const short8*)(ax + 32 + kh * 8);
    short8 sa0 = *(const short8*)(as + kh * 8);
    short8 sa1 = *(const short8*)(as + 32 + kh * 8);

    // msg MFMAs (chain feeds GELU) + gh MFMAs (stay in regs, consumed ph2)
    f32x4 amx = {0.f,0.f,0.f,0.f};
    amx = __builtin_amdgcn_mfma_f32_16x16x32_bf16(xa0, wm[0], amx, 0, 0, 0);
    amx = __builtin_amdgcn_mfma_f32_16x16x32_bf16(xa1, wm[1], amx, 0, 0, 0);
    f32x4 ams = {0.f,0.f,0.f,0.f};
    ams = __builtin_amdgcn_mfma_f32_16x16x32_bf16(sa0, wm[2], ams, 0, 0, 0);
    ams = __builtin_amdgcn_mfma_f32_16x16x32_bf16(sa1, wm[3], ams, 0, 0, 0);
    f32x4 agh[3];
    #pragma unroll
    for (int p = 0; p < 3; ++p) {
      f32x4 c = {0.f,0.f,0.f,0.f};
      c = __builtin_amdgcn_mfma_f32_16x16x32_bf16(sa0, wh[p][0], c, 0, 0, 0);
      c = __builtin_amdgcn_mfma_f32_16x16x32_bf16(sa1, wh[p][1], c, 0, 0, 0);
      agh[p] = c;
    }

    // GELU -> ms (gh MFMAs overlap this VALU block on the matrix pipe)
    #pragma unroll
    for (int i = 0; i < 4; ++i) {
      float a = amx[i] + ams[i] + btc;
      float g = 0.5f * a * (1.0f + ferf(a * 0.70710678118654752f));
      ms[(kh * 4 + i) * 72 + n] = f2bf(g);
    }
    btc = btn;
    BARRIER();  // B1: ms visible; xs/ss reads done

    // ================= PHASE 2 =================
    const unsigned short* am = &ms[(lane & 15) * 72];
    short8 ma0 = *(const short8*)(am + kh * 8);
    short8 ma1 = *(const short8*)(am + 32 + kh * 8);
    f32x4 agi[3];
    #pragma unroll
    for (int p = 0; p < 3; ++p) {
      f32x4 c = {0.f,0.f,0.f,0.f};
      c = __builtin_amdgcn_mfma_f32_16x16x32_bf16(ma0, wi[p][0], c, 0, 0, 0);
      c = __builtin_amdgcn_mfma_f32_16x16x32_bf16(ma1, wi[p][1], c, 0, 0, 0);
      agi[p] = c;
    }

    // gates (exp2-folded): rg = 1/(1+2^er), ng = 1 - 2/(1+2^yn)
    #pragma unroll
    for (int i = 0; i < 4; ++i) {
      const int rr = kh * 4 + i;
      float er = agi[0][i] + agh[0][i] + bsum0;
      float ez = agi[1][i] + agh[1][i] + bsum1;
      float rg = __builtin_amdgcn_rcpf(1.0f + fexp2(er));
      float zg = __builtin_amdgcn_rcpf(1.0f + fexp2(ez));
      float yn = fmaf(rg, agh[2][i] + bhh2, agi[2][i] + bih2);
      float ng = 1.0f - 2.0f * __builtin_amdgcn_rcpf(1.0f + fexp2(yn));
      float sn = fmaf(zg, s_reg[i] - ng, ng);
      s_reg[i] = sn;
      ss[rr * 72 + n] = f2bf(sn);
      out[((size_t)t * NROW + row0 + rr) * DD + n] = sn;  // fire-and-forget
    }
    // stage xs(t+1) from xv_use (loaded ph1(t-1): ~1.5 steps of latency cover)
    if (t + 1 < TT)
      *(unsigned long long*)&xs[fr * 72 + fd] = pack4(xv_use);
    BARRIER();  // B2: ss/xs updated for next step
  };

  // statically role-swapped 2x unroll (rule #20: no dynamic reg indexing)
  for (int tt = 0; tt < TT; tt += 2) {
    body(tt,     xvA, xvB);
    body(tt + 1, xvB, xvA);
  }
}

extern "C" void kernel_launch(void* const* d_in, const int* in_sizes, int n_in,
                              void* d_out, int out_size, void* d_ws, size_t ws_size,
                              hipStream_t stream) {
  const float* x      = (const float*)d_in[0];
  const int*   mask   = (const int*)  d_in[1];
  const float* msg_W  = (const float*)d_in[2];
  const float* msg_b  = (const float*)d_in[3];
  const float* W_ih   = (const float*)d_in[4];
  const float* W_hh   = (const float*)d_in[5];
  const float* b_ih   = (const float*)d_in[6];
  const float* b_hh   = (const float*)d_in[7];
  const float* freq   = (const float*)d_in[8];
  const float* phase  = (const float*)d_in[9];
  float* out    = (float*)d_out;
  float* bias_t = (float*)d_ws;   // TT*DD floats = 64 KB

  (void)in_sizes; (void)n_in; (void)out_size; (void)ws_size;

  bias_kernel<<<TT, DD, 0, stream>>>(msg_W, msg_b, freq, phase, bias_t);
  scan9<<<GRID, BLK, 0, stream>>>(x, mask, msg_W, W_ih, W_hh,
                                  b_ih, b_hh, bias_t, out);
}